// Round 2
// baseline (565.809 us; speedup 1.0000x reference)
//
#include <hip/hip_runtime.h>
#include <math.h>

#define N_NODES 1024
#define EDGE    4
#define DIM     64
#define ANND    16
#define STEPS   5
#define BATCH   4

__device__ __forceinline__ float fsigmoid(float x) {
    return 1.0f / (1.0f + __expf(-x));
}
__device__ __forceinline__ float ftanh(float x) {
    x = fminf(15.0f, fmaxf(-15.0f, x));
    float t = __expf(2.0f * x);
    return (t - 1.0f) / (t + 1.0f);
}

// ---------------------------------------------------------------------------
// prep: W1sum[e][d] = sum_f in_W[e][f][d]; combined transposed gate weights;
// transposed output weights. Total 29952 outputs -> 117 blocks x 256.
// wcomb layout: [6][64(d)][64(j)]  order: rC, rH, zC, zH, hC, hH
// ---------------------------------------------------------------------------
__global__ void prep(const float* __restrict__ inW, const float* __restrict__ rW,
                     const float* __restrict__ zW, const float* __restrict__ hW,
                     const float* __restrict__ o1W,
                     float* __restrict__ wcomb, float* __restrict__ w1s,
                     float* __restrict__ o1hT, float* __restrict__ o1aT)
{
    int id = blockIdx.x * 256 + threadIdx.x;
    if (id < 256) {
        int e = id >> 6, d = id & 63;
        float s = 0.0f;
        for (int f = 0; f < 64; ++f) s += inW[(e * 64 + f) * 64 + d];
        w1s[id] = s;
    }
    int i1 = id - 256;
    if (i1 >= 0 && i1 < 24576) {
        int mat = i1 >> 12, rem = i1 & 4095, d = rem >> 6, j = rem & 63;
        const float* W = (mat < 2) ? rW : (mat < 4) ? zW : hW;
        float v;
        if ((mat & 1) == 0) v = W[j * 192 + d] + W[j * 192 + 64 + d];  // a_in + a_out halves
        else                v = W[j * 192 + 128 + d];                  // h half
        wcomb[mat * 4096 + d * 64 + j] = v;
    }
    int i2 = id - 256 - 24576;
    if (i2 >= 0 && i2 < 4096) {
        int d = i2 >> 6, j = i2 & 63;
        o1hT[d * 64 + j] = o1W[j * 80 + d];
    }
    int i3 = id - 256 - 24576 - 4096;
    if (i3 >= 0 && i3 < 1024) {
        int a = i3 >> 6, j = i3 & 63;
        o1aT[a * 64 + j] = o1W[j * 80 + 64 + a];
    }
}

// ---------------------------------------------------------------------------
// gemm_ain: partial[chunk][b][n][d] = sum_{m in chunk} A[b][n][m] * X[m][d]
// where X[e*1024+mm][d] = h[b][mm][d]*W1sum[e][d] + in_b[e][d]  (built on the fly)
// grid (16, nsplit, 4), block 256. Tile 64(n) x 64(d), BK=64.
// Ash stored k-major (transposed) so compute reads are ds_read_b128.
// ---------------------------------------------------------------------------
__global__ __launch_bounds__(256) void gemm_ain(
    const float* __restrict__ A, const float* __restrict__ hbuf,
    const float* __restrict__ w1s, const float* __restrict__ inb,
    float* __restrict__ part, int kchunk)
{
    const int tid   = threadIdx.x;
    const int n0    = blockIdx.x * 64;
    const int chunk = blockIdx.y;
    const int b     = blockIdx.z;
    const int k0    = chunk * kchunk;
    const int e     = k0 >> 10;       // chunk lies inside one edge-type block
    const int m0    = k0 & 1023;
    const int niter = kchunk >> 6;

    __shared__ float Ash[64][68];   // [k][n-row], pad 68 keeps 16B align + spreads banks
    __shared__ float Xsh[64][68];   // [k][d]

    const int dbase = (tid & 3) * 4;
    float4 w1sv[4], ibv[4];
#pragma unroll
    for (int i = 0; i < 4; ++i) {
        w1sv[i] = *(const float4*)(w1s + e * 64 + dbase + 16 * i);
        ibv[i]  = *(const float4*)(inb + e * 64 + dbase + 16 * i);
    }

    const int arow = tid >> 4;          // 0..15
    const int acol = (tid & 15) * 4;    // 0..60
    const int xk   = tid >> 2;          // 0..63
    const float* Abase = A + (size_t)(b * N_NODES + n0) * 8192 + k0;
    const float* hbase = hbuf + (size_t)b * (N_NODES * DIM) + (size_t)m0 * DIM;

    float acc[4][4] = {};
    const int row0 = arow * 4;
    const int col0 = acol;

    for (int it = 0; it < niter; ++it) {
        const int kk = it * 64;
#pragma unroll
        for (int i = 0; i < 4; ++i) {   // A tile 64x64, store transposed
            int r = arow + 16 * i;
            float4 v = *(const float4*)(Abase + (size_t)r * 8192 + (kk + acol));
            Ash[acol + 0][r] = v.x;
            Ash[acol + 1][r] = v.y;
            Ash[acol + 2][r] = v.z;
            Ash[acol + 3][r] = v.w;
        }
#pragma unroll
        for (int i = 0; i < 4; ++i) {   // X tile 64x64 built from h * W1sum + in_b
            int d = dbase + 16 * i;
            float4 hv = *(const float4*)(hbase + (size_t)(kk + xk) * DIM + d);
            float4 xv;
            xv.x = fmaf(hv.x, w1sv[i].x, ibv[i].x);
            xv.y = fmaf(hv.y, w1sv[i].y, ibv[i].y);
            xv.z = fmaf(hv.z, w1sv[i].z, ibv[i].z);
            xv.w = fmaf(hv.w, w1sv[i].w, ibv[i].w);
            *(float4*)&Xsh[xk][d] = xv;
        }
        __syncthreads();
#pragma unroll 8
        for (int k2 = 0; k2 < 64; ++k2) {
            float4 av = *(const float4*)&Ash[k2][row0];
            float4 bv = *(const float4*)&Xsh[k2][col0];
            float a0 = av.x, a1 = av.y, a2 = av.z, a3 = av.w;
            float b0 = bv.x, b1 = bv.y, b2 = bv.z, b3 = bv.w;
            acc[0][0] = fmaf(a0, b0, acc[0][0]); acc[0][1] = fmaf(a0, b1, acc[0][1]);
            acc[0][2] = fmaf(a0, b2, acc[0][2]); acc[0][3] = fmaf(a0, b3, acc[0][3]);
            acc[1][0] = fmaf(a1, b0, acc[1][0]); acc[1][1] = fmaf(a1, b1, acc[1][1]);
            acc[1][2] = fmaf(a1, b2, acc[1][2]); acc[1][3] = fmaf(a1, b3, acc[1][3]);
            acc[2][0] = fmaf(a2, b0, acc[2][0]); acc[2][1] = fmaf(a2, b1, acc[2][1]);
            acc[2][2] = fmaf(a2, b2, acc[2][2]); acc[2][3] = fmaf(a2, b3, acc[2][3]);
            acc[3][0] = fmaf(a3, b0, acc[3][0]); acc[3][1] = fmaf(a3, b1, acc[3][1]);
            acc[3][2] = fmaf(a3, b2, acc[3][2]); acc[3][3] = fmaf(a3, b3, acc[3][3]);
        }
        __syncthreads();
    }

    float* P = part + (size_t)(chunk * BATCH + b) * (N_NODES * DIM) + (size_t)n0 * DIM;
#pragma unroll
    for (int i = 0; i < 4; ++i) {
        float4 o = make_float4(acc[i][0], acc[i][1], acc[i][2], acc[i][3]);
        *(float4*)&P[(size_t)(row0 + i) * DIM + col0] = o;
    }
}

// ---------------------------------------------------------------------------
// gate: per node, sum the K-split partials -> a_in, then GRU-style update.
// r = sig(a_in@rC + h@rH + rb); z likewise; hh = tanh(a_in@hC + (r*h)@hH + hb)
// h' = (1-z)h + z*hh.  16 nodes/block, 256 blocks.
// Weights are pre-transposed [d][j] so lane j loads are coalesced.
// ---------------------------------------------------------------------------
__global__ __launch_bounds__(256) void gate(
    const float* __restrict__ part, const float* __restrict__ wcomb,
    const float* __restrict__ rb, const float* __restrict__ zb,
    const float* __restrict__ hbias, float* __restrict__ h, int nsplit)
{
    __shared__ float ain_sh[16][64];
    __shared__ float h_sh[16][64];
    __shared__ float r_sh[16][64];
    const int tid = threadIdx.x;
    const int nodeBase = blockIdx.x * 16;

#pragma unroll
    for (int i = 0; i < 4; ++i) {
        int idx = tid + 256 * i;
        int nl = idx >> 6, d = idx & 63;
        int node = nodeBase + nl;
        float s = 0.0f;
        for (int c = 0; c < nsplit; ++c)
            s += part[((size_t)c * (BATCH * N_NODES) + node) * DIM + d];
        ain_sh[nl][d] = s;
        h_sh[nl][d] = h[(size_t)node * DIM + d];
    }
    __syncthreads();

    const int j  = tid & 63;
    const int ng = tid >> 6;
    const float* rCT = wcomb;
    const float* rHT = wcomb + 4096;
    const float* zCT = wcomb + 8192;
    const float* zHT = wcomb + 12288;
    const float* hCT = wcomb + 16384;
    const float* hHT = wcomb + 20480;

    float accr[4], accz[4];
#pragma unroll
    for (int i = 0; i < 4; ++i) { accr[i] = rb[j]; accz[i] = zb[j]; }
    for (int d = 0; d < 64; ++d) {
        float wrc = rCT[d * 64 + j], wrh = rHT[d * 64 + j];
        float wzc = zCT[d * 64 + j], wzh = zHT[d * 64 + j];
#pragma unroll
        for (int i = 0; i < 4; ++i) {
            int nl = ng * 4 + i;
            float av = ain_sh[nl][d], hv = h_sh[nl][d];
            accr[i] = fmaf(av, wrc, accr[i]); accr[i] = fmaf(hv, wrh, accr[i]);
            accz[i] = fmaf(av, wzc, accz[i]); accz[i] = fmaf(hv, wzh, accz[i]);
        }
    }
    float zreg[4];
#pragma unroll
    for (int i = 0; i < 4; ++i) {
        int nl = ng * 4 + i;
        r_sh[nl][j] = fsigmoid(accr[i]);
        zreg[i] = fsigmoid(accz[i]);
    }
    __syncthreads();

    float acch[4];
#pragma unroll
    for (int i = 0; i < 4; ++i) acch[i] = hbias[j];
    for (int d = 0; d < 64; ++d) {
        float whc = hCT[d * 64 + j], whh = hHT[d * 64 + j];
#pragma unroll
        for (int i = 0; i < 4; ++i) {
            int nl = ng * 4 + i;
            float av = ain_sh[nl][d];
            float rh = r_sh[nl][d] * h_sh[nl][d];
            acch[i] = fmaf(av, whc, acch[i]); acch[i] = fmaf(rh, whh, acch[i]);
        }
    }
#pragma unroll
    for (int i = 0; i < 4; ++i) {
        int nl = ng * 4 + i;
        int node = nodeBase + nl;
        float hh = ftanh(acch[i]);
        float z  = zreg[i];
        float ho = h_sh[nl][j];
        h[(size_t)node * DIM + j] = ho + z * (hh - ho);
    }
}

// ---------------------------------------------------------------------------
// outk: out[b,n] = sum_j tanh(h@o1h + ann@o1a + o1b)[j] * o2W[j] + o2b
// one wave per node, 4 nodes per block, 1024 blocks.
// ---------------------------------------------------------------------------
__global__ __launch_bounds__(256) void outk(
    const float* __restrict__ h, const float* __restrict__ ann,
    const float* __restrict__ o1hT, const float* __restrict__ o1aT,
    const float* __restrict__ o1b, const float* __restrict__ o2W,
    const float* __restrict__ o2b, float* __restrict__ out)
{
    __shared__ float h_sh[4][64];
    __shared__ float a_sh[4][16];
    const int tid = threadIdx.x;
    const int nodeBase = blockIdx.x * 4;
    {
        int nl = tid >> 6, d = tid & 63;
        h_sh[nl][d] = h[(size_t)(nodeBase + nl) * DIM + d];
    }
    if (tid < 64) {
        int nl = tid >> 4, a = tid & 15;
        a_sh[nl][a] = ann[(size_t)(nodeBase + nl) * ANND + a];
    }
    __syncthreads();
    const int j = tid & 63, nl = tid >> 6;
    float acc = o1b[j];
    for (int d = 0; d < 64; ++d) acc = fmaf(h_sh[nl][d], o1hT[d * 64 + j], acc);
    for (int a = 0; a < 16; ++a) acc = fmaf(a_sh[nl][a], o1aT[a * 64 + j], acc);
    float t = ftanh(acc) * o2W[j];
    for (int off = 32; off > 0; off >>= 1) t += __shfl_down(t, off);
    if (j == 0) out[nodeBase + nl] = t + o2b[0];
}

// ---------------------------------------------------------------------------
extern "C" void kernel_launch(void* const* d_in, const int* in_sizes, int n_in,
                              void* d_out, int out_size, void* d_ws, size_t ws_size,
                              hipStream_t stream)
{
    (void)in_sizes; (void)n_in; (void)out_size;
    const float* prop = (const float*)d_in[0];
    const float* ann  = (const float*)d_in[1];
    const float* A    = (const float*)d_in[2];
    const float* inW  = (const float*)d_in[3];
    const float* inb  = (const float*)d_in[4];
    // d_in[5] out_W, d_in[6] out_b: unused (reference sets a_out = a_in)
    const float* rW   = (const float*)d_in[7];
    const float* rb   = (const float*)d_in[8];
    const float* zW   = (const float*)d_in[9];
    const float* zb   = (const float*)d_in[10];
    const float* hW   = (const float*)d_in[11];
    const float* hb   = (const float*)d_in[12];
    const float* o1W  = (const float*)d_in[13];
    const float* o1b  = (const float*)d_in[14];
    const float* o2W  = (const float*)d_in[15];
    const float* o2b  = (const float*)d_in[16];
    float* out = (float*)d_out;
    float* ws  = (float*)d_ws;

    // K-split factor: 8 if the workspace allows (9.6 MB), else 4 (5.4 MB)
    int nsplit = 8;
    size_t need = ((size_t)(1 + 8) * 262144 + 29952) * sizeof(float);
    if (ws_size < need) nsplit = 4;
    const int kchunk = 4096 / nsplit;

    float* h_ws  = ws;                                   // [B][N][D]
    float* part  = ws + 262144;                          // [nsplit][B][N][D]
    float* wcomb = part + (size_t)nsplit * 262144;       // [6][64][64]
    float* w1s   = wcomb + 24576;                        // [E][D]
    float* o1hT  = w1s + 256;                            // [64][64]
    float* o1aT  = o1hT + 4096;                          // [16][64]

    prep<<<117, 256, 0, stream>>>(inW, rW, zW, hW, o1W, wcomb, w1s, o1hT, o1aT);
    hipMemcpyAsync(h_ws, prop, (size_t)262144 * sizeof(float),
                   hipMemcpyDeviceToDevice, stream);

    for (int s = 0; s < STEPS; ++s) {
        gemm_ain<<<dim3(16, nsplit, BATCH), 256, 0, stream>>>(A, h_ws, w1s, inb, part, kchunk);
        gate<<<256, 256, 0, stream>>>(part, wcomb, rb, zb, hb, h_ws, nsplit);
    }
    outk<<<1024, 256, 0, stream>>>(h_ws, ann, o1hT, o1aT, o1b, o2W, o2b, out);
}

// Round 4
// 406.186 us; speedup vs baseline: 1.3930x; 1.3930x over previous
//
#include <hip/hip_runtime.h>
#include <math.h>

#define N_NODES 1024
#define EDGE    4
#define DIM     64
#define ANND    16
#define STEPS   5
#define BATCH   4

typedef __attribute__((ext_vector_type(8))) short bf16x8;
typedef __attribute__((ext_vector_type(4))) float f32x4;

__device__ __forceinline__ float fsigmoid(float x) {
    return 1.0f / (1.0f + __expf(-x));
}
__device__ __forceinline__ float ftanh(float x) {
    x = fminf(15.0f, fmaxf(-15.0f, x));
    float t = __expf(2.0f * x);
    return (t - 1.0f) / (t + 1.0f);
}
__device__ __forceinline__ unsigned short f32_to_bf16(float x) {
    unsigned int u = __float_as_uint(x);
    unsigned int r = u + 0x7FFFu + ((u >> 16) & 1u);
    return (unsigned short)(r >> 16);
}

// ---------------------------------------------------------------------------
// prepA: A[:, :, :4096] f32 -> Ahi/Alo bf16 (hi/lo split), plus per-row
// per-edge sums rowsum[b*N+n][e] (exact f32, for the in_b term).
// One block per (b,n) row; wave w handles edge-chunk w (1024 cols).
// ---------------------------------------------------------------------------
__global__ __launch_bounds__(256) void prepA(
    const float* __restrict__ A, unsigned short* __restrict__ Ahi,
    unsigned short* __restrict__ Alo, float* __restrict__ rowsum)
{
    const int row = blockIdx.x;            // b*1024 + n
    const int t = threadIdx.x;
    const float* src = A + (size_t)row * 8192 + t * 16;
    alignas(16) unsigned short hs[16], ls[16];
    float s = 0.f;
#pragma unroll
    for (int i = 0; i < 4; ++i) {
        float4 v = *(const float4*)(src + i * 4);
        float vv[4] = {v.x, v.y, v.z, v.w};
#pragma unroll
        for (int j = 0; j < 4; ++j) {
            float x = vv[j];
            s += x;
            unsigned short hh = f32_to_bf16(x);
            float hf = __uint_as_float((unsigned int)hh << 16);
            hs[i * 4 + j] = hh;
            ls[i * 4 + j] = f32_to_bf16(x - hf);
        }
    }
    unsigned short* dh = Ahi + (size_t)row * 4096 + t * 16;
    unsigned short* dl = Alo + (size_t)row * 4096 + t * 16;
    *(uint4*)dh = *(const uint4*)&hs[0];
    *(uint4*)(dh + 8) = *(const uint4*)&hs[8];
    *(uint4*)dl = *(const uint4*)&ls[0];
    *(uint4*)(dl + 8) = *(const uint4*)&ls[8];
    // wave w == edge e (64 lanes x 16 cols = 1024 cols)
#pragma unroll
    for (int off = 32; off > 0; off >>= 1) s += __shfl_down(s, off);
    if ((t & 63) == 0) rowsum[(size_t)row * 4 + (t >> 6)] = s;
}

// ---------------------------------------------------------------------------
// prepW: W1sum[e][d]; combined transposed gate weights; transposed o1W.
// wcomb layout: [6][64(d)][64(j)]  order: rC, rH, zC, zH, hC, hH
// ---------------------------------------------------------------------------
__global__ void prepW(const float* __restrict__ inW, const float* __restrict__ rW,
                      const float* __restrict__ zW, const float* __restrict__ hW,
                      const float* __restrict__ o1W,
                      float* __restrict__ wcomb, float* __restrict__ w1s,
                      float* __restrict__ o1hT, float* __restrict__ o1aT)
{
    int id = blockIdx.x * 256 + threadIdx.x;
    if (id < 256) {
        int e = id >> 6, d = id & 63;
        float s = 0.0f;
        for (int f = 0; f < 64; ++f) s += inW[(e * 64 + f) * 64 + d];
        w1s[id] = s;
    }
    int i1 = id - 256;
    if (i1 >= 0 && i1 < 24576) {
        int mat = i1 >> 12, rem = i1 & 4095, d = rem >> 6, j = rem & 63;
        const float* W = (mat < 2) ? rW : (mat < 4) ? zW : hW;
        float v;
        if ((mat & 1) == 0) v = W[j * 192 + d] + W[j * 192 + 64 + d];
        else                v = W[j * 192 + 128 + d];
        wcomb[mat * 4096 + d * 64 + j] = v;
    }
    int i2 = id - 256 - 24576;
    if (i2 >= 0 && i2 < 4096) {
        int d = i2 >> 6, j = i2 & 63;
        o1hT[d * 64 + j] = o1W[j * 80 + d];
    }
    int i3 = id - 256 - 24576 - 4096;
    if (i3 >= 0 && i3 < 1024) {
        int a = i3 >> 6, j = i3 & 63;
        o1aT[a * 64 + j] = o1W[j * 80 + 64 + a];
    }
}

// ---------------------------------------------------------------------------
// transposeH: h[b][mm][d] f32 -> hThi/hTlo[b][d][mm] bf16 hi/lo.
// Grid 64 blocks: b = blk>>4, mm-tile = blk&15 (64 mm x 64 d per block).
// ---------------------------------------------------------------------------
__global__ __launch_bounds__(256) void transposeH(
    const float* __restrict__ h, unsigned short* __restrict__ hThi,
    unsigned short* __restrict__ hTlo)
{
    __shared__ float tile[64][65];
    const int bm = blockIdx.x & 15, b = blockIdx.x >> 4;
    const int t = threadIdx.x;
    {
        const int mml = t >> 2, d0 = (t & 3) * 16;
        const float* src = h + ((size_t)(b * 1024 + bm * 64 + mml)) * 64 + d0;
#pragma unroll
        for (int i = 0; i < 4; ++i) {
            float4 v = *(const float4*)(src + i * 4);
            tile[d0 + i * 4 + 0][mml] = v.x;
            tile[d0 + i * 4 + 1][mml] = v.y;
            tile[d0 + i * 4 + 2][mml] = v.z;
            tile[d0 + i * 4 + 3][mml] = v.w;
        }
    }
    __syncthreads();
    const int d = t >> 2, m0 = (t & 3) * 16;
    alignas(16) unsigned short hb[16], lb[16];
#pragma unroll
    for (int i = 0; i < 16; ++i) {
        float x = tile[d][m0 + i];
        unsigned short hh = f32_to_bf16(x);
        hb[i] = hh;
        lb[i] = f32_to_bf16(x - __uint_as_float((unsigned int)hh << 16));
    }
    unsigned short* dst = hThi + ((size_t)(b * 64 + d)) * 1024 + bm * 64 + m0;
    *(uint4*)dst = *(const uint4*)&hb[0];
    *(uint4*)(dst + 8) = *(const uint4*)&hb[8];
    unsigned short* dstl = hTlo + ((size_t)(b * 64 + d)) * 1024 + bm * 64 + m0;
    *(uint4*)dstl = *(const uint4*)&lb[0];
    *(uint4*)(dstl + 8) = *(const uint4*)&lb[8];
}

// ---------------------------------------------------------------------------
// gemm_mfma: part[chunk][b][n][d] = W1s[e][d] * sum_{k in chunk} A_e[n][k]·h[k][d]
// 3-pass split-bf16 MFMA (AhiXhi + AhiXlo + AloXhi ~= f32 accuracy).
// Grid (8 nblk, 8 chunk, 4 b), 256 thr = 4 waves x 32 rows (2 row-frags).
// X (=hT) staged in LDS per 64-k subtile with 16B-chunk XOR swizzle; A-frags
// loaded direct from global (each A element used exactly once).
// ---------------------------------------------------------------------------
__global__ __launch_bounds__(256) void gemm_mfma(
    const unsigned short* __restrict__ Ahi, const unsigned short* __restrict__ Alo,
    const unsigned short* __restrict__ hThi, const unsigned short* __restrict__ hTlo,
    const float* __restrict__ w1s, float* __restrict__ part)
{
    __shared__ unsigned short Xhs[64][64];
    __shared__ unsigned short Xls[64][64];
    const int tid = threadIdx.x;
    const int lane = tid & 63, wave = tid >> 6;
    const int nb = blockIdx.x, chunk = blockIdx.y, b = blockIdx.z;
    const int e = chunk >> 1, khalf = chunk & 1;
    const int rowbase = nb * 128 + wave * 32;

    // A fragment base (ushort units): row = rowbase + (lane&15) (+rf*16),
    // col = e*1024 + khalf*512 + sub*64 + ks*32 + (lane>>4)*8
    const size_t abase = ((size_t)(b * 1024 + rowbase + (lane & 15))) * 4096
                       + e * 1024 + khalf * 512 + ((lane >> 4) * 8);

    // X staging: idx = tid + 256*r -> d = idx>>3 (0..63), c = idx&7 (16B chunk)
    const int sd = tid >> 3;             // 0..31 (round 0); +32 (round 1)
    const int sc = tid & 7;
    const int scp = (sc ^ (sd & 7)) * 8; // swizzled chunk offset (ushort units)
    const int ldsoff0 = sd * 64 + scp;
    const int ldsoff1 = (sd + 32) * 64 + scp;   // (sd+32)&7 == sd&7
    const size_t xsrc = ((size_t)(b * 64 + sd)) * 1024 + khalf * 512 + sc * 8;
    const unsigned short* xh0 = hThi + xsrc;
    const unsigned short* xl0 = hTlo + xsrc;

    uint4 sH0 = *(const uint4*)(xh0);
    uint4 sH1 = *(const uint4*)(xh0 + 32 * 1024);
    uint4 sL0 = *(const uint4*)(xl0);
    uint4 sL1 = *(const uint4*)(xl0 + 32 * 1024);

    f32x4 acc[2][4] = {};

    for (int sub = 0; sub < 8; ++sub) {
        __syncthreads();
        *(uint4*)&((unsigned short*)Xhs)[ldsoff0] = sH0;
        *(uint4*)&((unsigned short*)Xhs)[ldsoff1] = sH1;
        *(uint4*)&((unsigned short*)Xls)[ldsoff0] = sL0;
        *(uint4*)&((unsigned short*)Xls)[ldsoff1] = sL1;
        __syncthreads();
        if (sub < 7) {
            const unsigned short* ph = xh0 + (sub + 1) * 64;
            const unsigned short* pl = xl0 + (sub + 1) * 64;
            sH0 = *(const uint4*)(ph);
            sH1 = *(const uint4*)(ph + 32 * 1024);
            sL0 = *(const uint4*)(pl);
            sL1 = *(const uint4*)(pl + 32 * 1024);
        }
        const size_t ak = abase + sub * 64;
#pragma unroll
        for (int ks = 0; ks < 2; ++ks) {
            bf16x8 a_hi[2], a_lo[2];
#pragma unroll
            for (int rf = 0; rf < 2; ++rf) {
                a_hi[rf] = *(const bf16x8*)(Ahi + ak + (size_t)rf * 16 * 4096 + ks * 32);
                a_lo[rf] = *(const bf16x8*)(Alo + ak + (size_t)rf * 16 * 4096 + ks * 32);
            }
#pragma unroll
            for (int df = 0; df < 4; ++df) {
                const int d = df * 16 + (lane & 15);
                const int cp = (((ks * 4) + (lane >> 4)) ^ (d & 7)) * 8;
                bf16x8 xh = *(const bf16x8*)&Xhs[d][cp];
                bf16x8 xl = *(const bf16x8*)&Xls[d][cp];
#pragma unroll
                for (int rf = 0; rf < 2; ++rf) {
                    acc[rf][df] = __builtin_amdgcn_mfma_f32_16x16x32_bf16(a_hi[rf], xh, acc[rf][df], 0, 0, 0);
                    acc[rf][df] = __builtin_amdgcn_mfma_f32_16x16x32_bf16(a_hi[rf], xl, acc[rf][df], 0, 0, 0);
                    acc[rf][df] = __builtin_amdgcn_mfma_f32_16x16x32_bf16(a_lo[rf], xh, acc[rf][df], 0, 0, 0);
                }
            }
        }
    }

    // epilogue: scale by W1s[e][d], store. C/D: col=lane&15, row=(lane>>4)*4+reg
    float* pbase = part + ((size_t)(chunk * 4 + b)) * 65536;
#pragma unroll
    for (int df = 0; df < 4; ++df) {
        const int d = df * 16 + (lane & 15);
        const float w = w1s[e * 64 + d];
#pragma unroll
        for (int rf = 0; rf < 2; ++rf) {
#pragma unroll
            for (int r = 0; r < 4; ++r) {
                int n = rowbase + rf * 16 + (lane >> 4) * 4 + r;
                pbase[(size_t)n * 64 + d] = acc[rf][df][r] * w;
            }
        }
    }
}

// ---------------------------------------------------------------------------
// gate: a_in = sum(partials) + rowsum·inb; GRU update; writes h (f32) and
// the transposed bf16 hi/lo h for the next step's gemm. Weights in LDS.
// ---------------------------------------------------------------------------
__global__ __launch_bounds__(256) void gate(
    const float* __restrict__ part, const float* __restrict__ wcomb,
    const float* __restrict__ rowsum, const float* __restrict__ inb,
    const float* __restrict__ rb, const float* __restrict__ zb,
    const float* __restrict__ hbias, float* __restrict__ h,
    unsigned short* __restrict__ hThi, unsigned short* __restrict__ hTlo)
{
    __shared__ float wl[24576];
    __shared__ float ain_sh[16][64];
    __shared__ float h_sh[16][64];
    __shared__ float r_sh[16][64];
    __shared__ float hn_sh[16][64];
    const int tid = threadIdx.x;
    const int nodeBase = blockIdx.x * 16;

#pragma unroll
    for (int i = 0; i < 24; ++i) {
        int idx = i * 256 + tid;
        *(float4*)&wl[idx * 4] = *(const float4*)&wcomb[idx * 4];
    }

#pragma unroll
    for (int i = 0; i < 4; ++i) {
        int idx = tid + 256 * i;
        int nl = idx >> 6, d = idx & 63;
        int node = nodeBase + nl;
        int bb = node >> 10, n = node & 1023;
        const float* pp = part + (size_t)bb * 65536 + (size_t)n * 64 + d;
        float s = 0.f;
#pragma unroll
        for (int c = 0; c < 8; ++c) s += pp[(size_t)c * 262144];
        const float* rs = rowsum + (size_t)node * 4;
#pragma unroll
        for (int e = 0; e < 4; ++e) s += rs[e] * inb[e * 64 + d];
        ain_sh[nl][d] = s;
        h_sh[nl][d] = h[(size_t)node * 64 + d];
    }
    __syncthreads();

    const int j  = tid & 63;
    const int ng = tid >> 6;
    const float* rCT = wl;
    const float* rHT = wl + 4096;
    const float* zCT = wl + 8192;
    const float* zHT = wl + 12288;
    const float* hCT = wl + 16384;
    const float* hHT = wl + 20480;

    float accr[4], accz[4];
#pragma unroll
    for (int i = 0; i < 4; ++i) { accr[i] = rb[j]; accz[i] = zb[j]; }
    for (int d = 0; d < 64; ++d) {
        float wrc = rCT[d * 64 + j], wrh = rHT[d * 64 + j];
        float wzc = zCT[d * 64 + j], wzh = zHT[d * 64 + j];
#pragma unroll
        for (int i = 0; i < 4; ++i) {
            int nl = ng * 4 + i;
            float av = ain_sh[nl][d], hv = h_sh[nl][d];
            accr[i] = fmaf(av, wrc, accr[i]); accr[i] = fmaf(hv, wrh, accr[i]);
            accz[i] = fmaf(av, wzc, accz[i]); accz[i] = fmaf(hv, wzh, accz[i]);
        }
    }
    float zreg[4];
#pragma unroll
    for (int i = 0; i < 4; ++i) {
        int nl = ng * 4 + i;
        r_sh[nl][j] = fsigmoid(accr[i]);
        zreg[i] = fsigmoid(accz[i]);
    }
    __syncthreads();

    float acch[4];
#pragma unroll
    for (int i = 0; i < 4; ++i) acch[i] = hbias[j];
    for (int d = 0; d < 64; ++d) {
        float whc = hCT[d * 64 + j], whh = hHT[d * 64 + j];
#pragma unroll
        for (int i = 0; i < 4; ++i) {
            int nl = ng * 4 + i;
            float av = ain_sh[nl][d];
            float rh = r_sh[nl][d] * h_sh[nl][d];
            acch[i] = fmaf(av, whc, acch[i]); acch[i] = fmaf(rh, whh, acch[i]);
        }
    }
#pragma unroll
    for (int i = 0; i < 4; ++i) {
        int nl = ng * 4 + i;
        int node = nodeBase + nl;
        float hh = ftanh(acch[i]);
        float ho = h_sh[nl][j];
        float hnew = ho + zreg[i] * (hh - ho);
        h[(size_t)node * 64 + j] = hnew;
        hn_sh[nl][j] = hnew;
    }
    __syncthreads();

    // transposed bf16 hi/lo write: thread t -> d = t>>2, quad q = t&3
    {
        const int d = tid >> 2, q = tid & 3;
        const int bb = nodeBase >> 10;
        const int mm0 = (nodeBase & 1023) + q * 4;
        alignas(8) unsigned short hb4[4], lb4[4];
#pragma unroll
        for (int i = 0; i < 4; ++i) {
            float x = hn_sh[q * 4 + i][d];
            unsigned short hh = f32_to_bf16(x);
            hb4[i] = hh;
            lb4[i] = f32_to_bf16(x - __uint_as_float((unsigned int)hh << 16));
        }
        unsigned short* dst = hThi + ((size_t)(bb * 64 + d)) * 1024 + mm0;
        *(uint2*)dst = *(const uint2*)hb4;
        unsigned short* dstl = hTlo + ((size_t)(bb * 64 + d)) * 1024 + mm0;
        *(uint2*)dstl = *(const uint2*)lb4;
    }
}

// ---------------------------------------------------------------------------
// outk: out[b,n] = sum_j tanh(h@o1h + ann@o1a + o1b)[j] * o2W[j] + o2b
// ---------------------------------------------------------------------------
__global__ __launch_bounds__(256) void outk(
    const float* __restrict__ h, const float* __restrict__ ann,
    const float* __restrict__ o1hT, const float* __restrict__ o1aT,
    const float* __restrict__ o1b, const float* __restrict__ o2W,
    const float* __restrict__ o2b, float* __restrict__ out)
{
    __shared__ float h_sh[4][64];
    __shared__ float a_sh[4][16];
    const int tid = threadIdx.x;
    const int nodeBase = blockIdx.x * 4;
    {
        int nl = tid >> 6, d = tid & 63;
        h_sh[nl][d] = h[(size_t)(nodeBase + nl) * 64 + d];
    }
    if (tid < 64) {
        int nl = tid >> 4, a = tid & 15;
        a_sh[nl][a] = ann[(size_t)(nodeBase + nl) * 16 + a];
    }
    __syncthreads();
    const int j = tid & 63, nl = tid >> 6;
    float acc = o1b[j];
    for (int d = 0; d < 64; ++d) acc = fmaf(h_sh[nl][d], o1hT[d * 64 + j], acc);
    for (int a = 0; a < 16; ++a) acc = fmaf(a_sh[nl][a], o1aT[a * 64 + j], acc);
    float t = ftanh(acc) * o2W[j];
    for (int off = 32; off > 0; off >>= 1) t += __shfl_down(t, off);
    if (j == 0) out[nodeBase + nl] = t + o2b[0];
}

// ---------------------------------------------------------------------------
extern "C" void kernel_launch(void* const* d_in, const int* in_sizes, int n_in,
                              void* d_out, int out_size, void* d_ws, size_t ws_size,
                              hipStream_t stream)
{
    (void)in_sizes; (void)n_in; (void)out_size; (void)ws_size;
    const float* prop = (const float*)d_in[0];
    const float* ann  = (const float*)d_in[1];
    const float* A    = (const float*)d_in[2];
    const float* inW  = (const float*)d_in[3];
    const float* inb  = (const float*)d_in[4];
    // d_in[5] out_W, d_in[6] out_b unused (a_out = a_in in the reference)
    const float* rW   = (const float*)d_in[7];
    const float* rb   = (const float*)d_in[8];
    const float* zW   = (const float*)d_in[9];
    const float* zb   = (const float*)d_in[10];
    const float* hW   = (const float*)d_in[11];
    const float* hb   = (const float*)d_in[12];
    const float* o1W  = (const float*)d_in[13];
    const float* o1b  = (const float*)d_in[14];
    const float* o2W  = (const float*)d_in[15];
    const float* o2b  = (const float*)d_in[16];
    float* out = (float*)d_out;

    // workspace layout (ws_size observed ~512 MiB; total need ~78 MB)
    char* base = (char*)d_ws;
    float* h_ws   = (float*)base;                         // 262144 f32
    float* part   = h_ws + 262144;                        // 8*262144 f32
    float* wcomb  = part + 8 * 262144;                    // 24576
    float* w1s    = wcomb + 24576;                        // 256
    float* o1hT   = w1s + 256;                            // 4096
    float* o1aT   = o1hT + 4096;                          // 1024
    float* rowsum = o1aT + 1024;                          // 16384
    unsigned short* Ahi  = (unsigned short*)(rowsum + 16384);   // 16.78M bf16
    unsigned short* Alo  = Ahi + (size_t)16777216;
    unsigned short* hThi = Alo + (size_t)16777216;              // 262144 bf16
    unsigned short* hTlo = hThi + 262144;

    prepA<<<4096, 256, 0, stream>>>(A, Ahi, Alo, rowsum);
    prepW<<<117, 256, 0, stream>>>(inW, rW, zW, hW, o1W, wcomb, w1s, o1hT, o1aT);
    hipMemcpyAsync(h_ws, prop, (size_t)262144 * sizeof(float),
                   hipMemcpyDeviceToDevice, stream);
    transposeH<<<64, 256, 0, stream>>>(h_ws, hThi, hTlo);

    for (int s = 0; s < STEPS; ++s) {
        gemm_mfma<<<dim3(8, 8, 4), 256, 0, stream>>>(Ahi, Alo, hThi, hTlo, w1s, part);
        gate<<<256, 256, 0, stream>>>(part, wcomb, rowsum, inb, rb, zb, hb,
                                      h_ws, hThi, hTlo);
    }
    outk<<<1024, 256, 0, stream>>>(h_ws, ann, o1hT, o1aT, o1b, o2W, o2b, out);
}

// Round 6
// 403.920 us; speedup vs baseline: 1.4008x; 1.0056x over previous
//
#include <hip/hip_runtime.h>
#include <math.h>

#define N_NODES 1024
#define EDGE    4
#define DIM     64
#define ANND    16
#define STEPS   5
#define BATCH   4

typedef __attribute__((ext_vector_type(8))) short bf16x8;
typedef __attribute__((ext_vector_type(4))) float f32x4;

__device__ __forceinline__ float fsigmoid(float x) {
    return 1.0f / (1.0f + __expf(-x));
}
__device__ __forceinline__ float ftanh(float x) {
    x = fminf(15.0f, fmaxf(-15.0f, x));
    float t = __expf(2.0f * x);
    return (t - 1.0f) / (t + 1.0f);
}
__device__ __forceinline__ unsigned short f32_to_bf16(float x) {
    unsigned int u = __float_as_uint(x);
    unsigned int r = u + 0x7FFFu + ((u >> 16) & 1u);
    return (unsigned short)(r >> 16);
}

// ---------------------------------------------------------------------------
// prepA: A[:, :, :4096] f32 -> Ahl bf16 hi/lo interleaved per 8-elem chunk:
// Ahl[row][c][0:8]=hi, [8:16]=lo  (so a lane's hi+lo frag pair is 32B
// contiguous -> full-cache-line wave access). Also rowsum[row][e].
// ---------------------------------------------------------------------------
__global__ __launch_bounds__(256) void prepA(
    const float* __restrict__ A, unsigned short* __restrict__ Ahl,
    float* __restrict__ rowsum)
{
    const int row = blockIdx.x;            // b*1024 + n
    const int t = threadIdx.x;
    const float* src = A + (size_t)row * 8192 + t * 16;
    unsigned short* dst = Ahl + (size_t)row * 8192 + t * 32;
    float s = 0.f;
#pragma unroll
    for (int c = 0; c < 2; ++c) {          // two 8-wide chunks per thread
        alignas(16) unsigned short hs[8], ls[8];
#pragma unroll
        for (int i = 0; i < 2; ++i) {
            float4 v = *(const float4*)(src + c * 8 + i * 4);
            float vv[4] = {v.x, v.y, v.z, v.w};
#pragma unroll
            for (int j = 0; j < 4; ++j) {
                float x = vv[j];
                s += x;
                unsigned short hh = f32_to_bf16(x);
                hs[i * 4 + j] = hh;
                ls[i * 4 + j] = f32_to_bf16(x - __uint_as_float((unsigned int)hh << 16));
            }
        }
        *(uint4*)(dst + c * 16)     = *(const uint4*)hs;
        *(uint4*)(dst + c * 16 + 8) = *(const uint4*)ls;
    }
    // wave w == edge e (64 lanes x 16 cols = 1024 cols)
#pragma unroll
    for (int off = 32; off > 0; off >>= 1) s += __shfl_down(s, off);
    if ((t & 63) == 0) rowsum[(size_t)row * 4 + (t >> 6)] = s;
}

// ---------------------------------------------------------------------------
// prepW: W1sum[e][d]; combined transposed gate weights; transposed o1W.
// wcomb layout: [6][64(d)][64(j)]  order: rC, rH, zC, zH, hC, hH
// ---------------------------------------------------------------------------
__global__ void prepW(const float* __restrict__ inW, const float* __restrict__ rW,
                      const float* __restrict__ zW, const float* __restrict__ hW,
                      const float* __restrict__ o1W,
                      float* __restrict__ wcomb, float* __restrict__ w1s,
                      float* __restrict__ o1hT, float* __restrict__ o1aT)
{
    int id = blockIdx.x * 256 + threadIdx.x;
    if (id < 256) {
        int e = id >> 6, d = id & 63;
        float s = 0.0f;
        for (int f = 0; f < 64; ++f) s += inW[(e * 64 + f) * 64 + d];
        w1s[id] = s;
    }
    int i1 = id - 256;
    if (i1 >= 0 && i1 < 24576) {
        int mat = i1 >> 12, rem = i1 & 4095, d = rem >> 6, j = rem & 63;
        const float* W = (mat < 2) ? rW : (mat < 4) ? zW : hW;
        float v;
        if ((mat & 1) == 0) v = W[j * 192 + d] + W[j * 192 + 64 + d];
        else                v = W[j * 192 + 128 + d];
        wcomb[mat * 4096 + d * 64 + j] = v;
    }
    int i2 = id - 256 - 24576;
    if (i2 >= 0 && i2 < 4096) {
        int d = i2 >> 6, j = i2 & 63;
        o1hT[d * 64 + j] = o1W[j * 80 + d];
    }
    int i3 = id - 256 - 24576 - 4096;
    if (i3 >= 0 && i3 < 1024) {
        int a = i3 >> 6, j = i3 & 63;
        o1aT[a * 64 + j] = o1W[j * 80 + 64 + a];
    }
}

// ---------------------------------------------------------------------------
// transposeH: h[b][mm][d] f32 -> hThi/hTlo[b][d][mm] bf16 hi/lo.
// ---------------------------------------------------------------------------
__global__ __launch_bounds__(256) void transposeH(
    const float* __restrict__ h, unsigned short* __restrict__ hThi,
    unsigned short* __restrict__ hTlo)
{
    __shared__ float tile[64][65];
    const int bm = blockIdx.x & 15, b = blockIdx.x >> 4;
    const int t = threadIdx.x;
    {
        const int mml = t >> 2, d0 = (t & 3) * 16;
        const float* src = h + ((size_t)(b * 1024 + bm * 64 + mml)) * 64 + d0;
#pragma unroll
        for (int i = 0; i < 4; ++i) {
            float4 v = *(const float4*)(src + i * 4);
            tile[d0 + i * 4 + 0][mml] = v.x;
            tile[d0 + i * 4 + 1][mml] = v.y;
            tile[d0 + i * 4 + 2][mml] = v.z;
            tile[d0 + i * 4 + 3][mml] = v.w;
        }
    }
    __syncthreads();
    const int d = t >> 2, m0 = (t & 3) * 16;
    alignas(16) unsigned short hb[16], lb[16];
#pragma unroll
    for (int i = 0; i < 16; ++i) {
        float x = tile[d][m0 + i];
        unsigned short hh = f32_to_bf16(x);
        hb[i] = hh;
        lb[i] = f32_to_bf16(x - __uint_as_float((unsigned int)hh << 16));
    }
    unsigned short* dst = hThi + ((size_t)(b * 64 + d)) * 1024 + bm * 64 + m0;
    *(uint4*)dst = *(const uint4*)&hb[0];
    *(uint4*)(dst + 8) = *(const uint4*)&hb[8];
    unsigned short* dstl = hTlo + ((size_t)(b * 64 + d)) * 1024 + bm * 64 + m0;
    *(uint4*)dstl = *(const uint4*)&lb[0];
    *(uint4*)(dstl + 8) = *(const uint4*)&lb[8];
}

// ---------------------------------------------------------------------------
// gemm_mfma: part[chunk][b][n][d] = W1s[e][d] * sum_{k in chunk} A_e[n][k]·h[k][d]
// 3-pass split-bf16 MFMA. Grid (16 nb, 16 chunk, 4 b) = 1024 blocks =
// 4 blocks/CU = 4 waves/SIMD (the round-4 version ran at 1 wave/SIMD and was
// ~98% latency-stalled). Each chunk = 256 k inside one edge-type block.
// Wave handles 16 rows x 64 d. X staged in LDS (XOR-swizzled); A-frags
// direct from global (zero reuse), hi/lo pair 32B-contiguous.
// ---------------------------------------------------------------------------
__global__ __launch_bounds__(256, 4) void gemm_mfma(
    const unsigned short* __restrict__ Ahl,
    const unsigned short* __restrict__ hThi, const unsigned short* __restrict__ hTlo,
    const float* __restrict__ w1s, float* __restrict__ part)
{
    __shared__ unsigned short Xhs[64][64];
    __shared__ unsigned short Xls[64][64];
    const int tid = threadIdx.x;
    const int lane = tid & 63, wave = tid >> 6;
    const int nb = blockIdx.x, chunk = blockIdx.y, b = blockIdx.z;
    const int e = chunk >> 2, kq = chunk & 3;
    const int rowbase = nb * 64 + wave * 16;

    // A chunk index = e*128 + kq*32 + sub*8 + ks*4 + (lane>>4); 16 ushorts each
    const size_t abase = ((size_t)(b * 1024 + rowbase + (lane & 15))) * 8192
                       + (size_t)(e * 128 + kq * 32 + (lane >> 4)) * 16;

    // X staging: thread -> sd = tid>>3 (d-row, +32 second round), sc = 16B chunk
    const int sd = tid >> 3;
    const int sc = tid & 7;
    const int scp = (sc ^ (sd & 7)) * 8;         // XOR swizzle (bank spread)
    const int ldsoff0 = sd * 64 + scp;
    const int ldsoff1 = (sd + 32) * 64 + scp;    // (sd+32)&7 == sd&7
    const size_t xsrc = ((size_t)(b * 64 + sd)) * 1024 + kq * 256 + sc * 8;
    const unsigned short* xh0 = hThi + xsrc;
    const unsigned short* xl0 = hTlo + xsrc;

    uint4 sH0 = *(const uint4*)(xh0);
    uint4 sH1 = *(const uint4*)(xh0 + 32 * 1024);
    uint4 sL0 = *(const uint4*)(xl0);
    uint4 sL1 = *(const uint4*)(xl0 + 32 * 1024);

    f32x4 acc[4] = {};

#pragma unroll
    for (int sub = 0; sub < 4; ++sub) {
        __syncthreads();
        *(uint4*)&((unsigned short*)Xhs)[ldsoff0] = sH0;
        *(uint4*)&((unsigned short*)Xhs)[ldsoff1] = sH1;
        *(uint4*)&((unsigned short*)Xls)[ldsoff0] = sL0;
        *(uint4*)&((unsigned short*)Xls)[ldsoff1] = sL1;
        __syncthreads();
        if (sub < 3) {
            const unsigned short* ph = xh0 + (sub + 1) * 64;
            const unsigned short* pl = xl0 + (sub + 1) * 64;
            sH0 = *(const uint4*)(ph);
            sH1 = *(const uint4*)(ph + 32 * 1024);
            sL0 = *(const uint4*)(pl);
            sL1 = *(const uint4*)(pl + 32 * 1024);
        }
#pragma unroll
        for (int ks = 0; ks < 2; ++ks) {
            const unsigned short* ap = Ahl + abase + (size_t)(sub * 8 + ks * 4) * 16;
            bf16x8 a_hi = *(const bf16x8*)(ap);
            bf16x8 a_lo = *(const bf16x8*)(ap + 8);
#pragma unroll
            for (int df = 0; df < 4; ++df) {
                const int d = df * 16 + (lane & 15);
                const int cp = (((ks * 4) + (lane >> 4)) ^ (d & 7)) * 8;
                bf16x8 xh = *(const bf16x8*)&Xhs[d][cp];
                bf16x8 xl = *(const bf16x8*)&Xls[d][cp];
                acc[df] = __builtin_amdgcn_mfma_f32_16x16x32_bf16(a_hi, xh, acc[df], 0, 0, 0);
                acc[df] = __builtin_amdgcn_mfma_f32_16x16x32_bf16(a_hi, xl, acc[df], 0, 0, 0);
                acc[df] = __builtin_amdgcn_mfma_f32_16x16x32_bf16(a_lo, xh, acc[df], 0, 0, 0);
            }
        }
    }

    // epilogue: scale by W1s[e][d]. C/D: col=lane&15, row=(lane>>4)*4+reg
    float* pbase = part + ((size_t)(chunk * 4 + b)) * 65536;
#pragma unroll
    for (int df = 0; df < 4; ++df) {
        const int d = df * 16 + (lane & 15);
        const float w = w1s[e * 64 + d];
#pragma unroll
        for (int r = 0; r < 4; ++r) {
            int n = rowbase + (lane >> 4) * 4 + r;
            pbase[(size_t)n * 64 + d] = acc[df][r] * w;
        }
    }
}

// ---------------------------------------------------------------------------
// gate: a_in = sum(16 partials) + rowsum·inb; GRU update; writes h (f32) and
// the transposed bf16 hi/lo h for the next step's gemm. Weights in LDS.
// ---------------------------------------------------------------------------
__global__ __launch_bounds__(256) void gate(
    const float* __restrict__ part, const float* __restrict__ wcomb,
    const float* __restrict__ rowsum, const float* __restrict__ inb,
    const float* __restrict__ rb, const float* __restrict__ zb,
    const float* __restrict__ hbias, float* __restrict__ h,
    unsigned short* __restrict__ hThi, unsigned short* __restrict__ hTlo)
{
    __shared__ float wl[24576];
    __shared__ float ain_sh[16][64];
    __shared__ float h_sh[16][64];
    __shared__ float r_sh[16][64];
    __shared__ float hn_sh[16][64];
    const int tid = threadIdx.x;
    const int nodeBase = blockIdx.x * 16;

#pragma unroll
    for (int i = 0; i < 24; ++i) {
        int idx = i * 256 + tid;
        *(float4*)&wl[idx * 4] = *(const float4*)&wcomb[idx * 4];
    }

#pragma unroll
    for (int i = 0; i < 4; ++i) {
        int idx = tid + 256 * i;
        int nl = idx >> 6, d = idx & 63;
        int node = nodeBase + nl;
        int bb = node >> 10, n = node & 1023;
        const float* pp = part + (size_t)bb * 65536 + (size_t)n * 64 + d;
        float s = 0.f;
#pragma unroll
        for (int c = 0; c < 16; ++c) s += pp[(size_t)c * 262144];
        const float* rs = rowsum + (size_t)node * 4;
#pragma unroll
        for (int e = 0; e < 4; ++e) s += rs[e] * inb[e * 64 + d];
        ain_sh[nl][d] = s;
        h_sh[nl][d] = h[(size_t)node * 64 + d];
    }
    __syncthreads();

    const int j  = tid & 63;
    const int ng = tid >> 6;
    const float* rCT = wl;
    const float* rHT = wl + 4096;
    const float* zCT = wl + 8192;
    const float* zHT = wl + 12288;
    const float* hCT = wl + 16384;
    const float* hHT = wl + 20480;

    float accr[4], accz[4];
#pragma unroll
    for (int i = 0; i < 4; ++i) { accr[i] = rb[j]; accz[i] = zb[j]; }
    for (int d = 0; d < 64; ++d) {
        float wrc = rCT[d * 64 + j], wrh = rHT[d * 64 + j];
        float wzc = zCT[d * 64 + j], wzh = zHT[d * 64 + j];
#pragma unroll
        for (int i = 0; i < 4; ++i) {
            int nl = ng * 4 + i;
            float av = ain_sh[nl][d], hv = h_sh[nl][d];
            accr[i] = fmaf(av, wrc, accr[i]); accr[i] = fmaf(hv, wrh, accr[i]);
            accz[i] = fmaf(av, wzc, accz[i]); accz[i] = fmaf(hv, wzh, accz[i]);
        }
    }
    float zreg[4];
#pragma unroll
    for (int i = 0; i < 4; ++i) {
        int nl = ng * 4 + i;
        r_sh[nl][j] = fsigmoid(accr[i]);
        zreg[i] = fsigmoid(accz[i]);
    }
    __syncthreads();

    float acch[4];
#pragma unroll
    for (int i = 0; i < 4; ++i) acch[i] = hbias[j];
    for (int d = 0; d < 64; ++d) {
        float whc = hCT[d * 64 + j], whh = hHT[d * 64 + j];
#pragma unroll
        for (int i = 0; i < 4; ++i) {
            int nl = ng * 4 + i;
            float av = ain_sh[nl][d];
            float rh = r_sh[nl][d] * h_sh[nl][d];
            acch[i] = fmaf(av, whc, acch[i]); acch[i] = fmaf(rh, whh, acch[i]);
        }
    }
#pragma unroll
    for (int i = 0; i < 4; ++i) {
        int nl = ng * 4 + i;
        int node = nodeBase + nl;
        float hh = ftanh(acch[i]);
        float ho = h_sh[nl][j];
        float hnew = ho + zreg[i] * (hh - ho);
        h[(size_t)node * 64 + j] = hnew;
        hn_sh[nl][j] = hnew;
    }
    __syncthreads();

    // transposed bf16 hi/lo write: thread t -> d = t>>2, quad q = t&3
    {
        const int d = tid >> 2, q = tid & 3;
        const int bb = nodeBase >> 10;
        const int mm0 = (nodeBase & 1023) + q * 4;
        alignas(8) unsigned short hb4[4], lb4[4];
#pragma unroll
        for (int i = 0; i < 4; ++i) {
            float x = hn_sh[q * 4 + i][d];
            unsigned short hh = f32_to_bf16(x);
            hb4[i] = hh;
            lb4[i] = f32_to_bf16(x - __uint_as_float((unsigned int)hh << 16));
        }
        unsigned short* dst = hThi + ((size_t)(bb * 64 + d)) * 1024 + mm0;
        *(uint2*)dst = *(const uint2*)hb4;
        unsigned short* dstl = hTlo + ((size_t)(bb * 64 + d)) * 1024 + mm0;
        *(uint2*)dstl = *(const uint2*)lb4;
    }
}

// ---------------------------------------------------------------------------
// outk: out[b,n] = sum_j tanh(h@o1h + ann@o1a + o1b)[j] * o2W[j] + o2b
// ---------------------------------------------------------------------------
__global__ __launch_bounds__(256) void outk(
    const float* __restrict__ h, const float* __restrict__ ann,
    const float* __restrict__ o1hT, const float* __restrict__ o1aT,
    const float* __restrict__ o1b, const float* __restrict__ o2W,
    const float* __restrict__ o2b, float* __restrict__ out)
{
    __shared__ float h_sh[4][64];
    __shared__ float a_sh[4][16];
    const int tid = threadIdx.x;
    const int nodeBase = blockIdx.x * 4;
    {
        int nl = tid >> 6, d = tid & 63;
        h_sh[nl][d] = h[(size_t)(nodeBase + nl) * 64 + d];
    }
    if (tid < 64) {
        int nl = tid >> 4, a = tid & 15;
        a_sh[nl][a] = ann[(size_t)(nodeBase + nl) * 16 + a];
    }
    __syncthreads();
    const int j = tid & 63, nl = tid >> 6;
    float acc = o1b[j];
    for (int d = 0; d < 64; ++d) acc = fmaf(h_sh[nl][d], o1hT[d * 64 + j], acc);
    for (int a = 0; a < 16; ++a) acc = fmaf(a_sh[nl][a], o1aT[a * 64 + j], acc);
    float t = ftanh(acc) * o2W[j];
    for (int off = 32; off > 0; off >>= 1) t += __shfl_down(t, off);
    if (j == 0) out[nodeBase + nl] = t + o2b[0];
}

// ---------------------------------------------------------------------------
extern "C" void kernel_launch(void* const* d_in, const int* in_sizes, int n_in,
                              void* d_out, int out_size, void* d_ws, size_t ws_size,
                              hipStream_t stream)
{
    (void)in_sizes; (void)n_in; (void)out_size; (void)ws_size;
    const float* prop = (const float*)d_in[0];
    const float* ann  = (const float*)d_in[1];
    const float* A    = (const float*)d_in[2];
    const float* inW  = (const float*)d_in[3];
    const float* inb  = (const float*)d_in[4];
    // d_in[5] out_W, d_in[6] out_b unused (a_out = a_in in the reference)
    const float* rW   = (const float*)d_in[7];
    const float* rb   = (const float*)d_in[8];
    const float* zW   = (const float*)d_in[9];
    const float* zb   = (const float*)d_in[10];
    const float* hW   = (const float*)d_in[11];
    const float* hb   = (const float*)d_in[12];
    const float* o1W  = (const float*)d_in[13];
    const float* o1b  = (const float*)d_in[14];
    const float* o2W  = (const float*)d_in[15];
    const float* o2b  = (const float*)d_in[16];
    float* out = (float*)d_out;

    // workspace layout (~86 MB of the ~512 MiB ws)
    float* h_ws   = (float*)d_ws;                         // 262144
    float* part   = h_ws + 262144;                        // 16*262144
    float* wcomb  = part + 16 * 262144;                   // 24576
    float* w1s    = wcomb + 24576;                        // 256
    float* o1hT   = w1s + 256;                            // 4096
    float* o1aT   = o1hT + 4096;                          // 1024
    float* rowsum = o1aT + 1024;                          // 16384
    unsigned short* Ahl  = (unsigned short*)(rowsum + 16384);   // 33.5M ushort
    unsigned short* hThi = Ahl + (size_t)33554432;              // 262144
    unsigned short* hTlo = hThi + 262144;

    prepA<<<4096, 256, 0, stream>>>(A, Ahl, rowsum);
    prepW<<<117, 256, 0, stream>>>(inW, rW, zW, hW, o1W, wcomb, w1s, o1hT, o1aT);
    hipMemcpyAsync(h_ws, prop, (size_t)262144 * sizeof(float),
                   hipMemcpyDeviceToDevice, stream);
    transposeH<<<64, 256, 0, stream>>>(h_ws, hThi, hTlo);

    for (int s = 0; s < STEPS; ++s) {
        gemm_mfma<<<dim3(16, 16, 4), 256, 0, stream>>>(Ahl, hThi, hTlo, w1s, part);
        gate<<<256, 256, 0, stream>>>(part, wcomb, rowsum, inb, rb, zb, hb,
                                      h_ws, hThi, hTlo);
    }
    outk<<<1024, 256, 0, stream>>>(h_ws, ann, o1hT, o1aT, o1b, o2W, o2b, out);
}